// Round 2
// baseline (5926.148 us; speedup 1.0000x reference)
//
#include <hip/hip_runtime.h>

// ---- problem constants -----------------------------------------------------
#define PRECISE 1        // 1: bf16 hi/lo split (fp32-accurate), 0: plain bf16
#define BTOT   4096      // batch
#define TWARM  64        // warm timesteps
#define FIN    64        // input features
#define UDIM   256       // hidden units
#define ZDIM   1024      // 4*U gate pre-activations
#define KDIM   320       // FIN + UDIM (concat [x|h] @ [K;R])
#define OSTEPS 24
#define OCOLS  65        // dense out dim (F+1)
#define OCPAD  80        // padded to 5 col-tiles of 16
#define BR     64        // batch rows per block  (R2: 32 -> 64, halves W traffic)
#define NB     (BTOT / BR)   // 64 blocks
#define ASTR   344       // LDS A row stride in bf16 (320 + 24 pad)
#define NTHR   512       // 8 waves
#define MT     (BR / 16) // 4 row-tiles per wave

// W packed layout: per z-col 640 shorts: group g8=k>>3 at col*640 + g8*16,
// hi8 at +0..7, lo8 at +8..15  -> one contiguous 32B per lane per (kt,ct).
#define WCOL   640
// Dense W packed: per col 512 shorts, same hi8|lo8 interleave.
#define DCOL   512

typedef short bf16x8 __attribute__((ext_vector_type(8)));
typedef short s16x4  __attribute__((ext_vector_type(4)));
typedef float f32x4  __attribute__((ext_vector_type(4)));

static __device__ __forceinline__ short f2bf(float x) {  // RNE f32 -> bf16 bits
  unsigned u = __float_as_uint(x);
  return (short)((u + 0x7fffu + ((u >> 16) & 1u)) >> 16);
}
static __device__ __forceinline__ float bf2f(short h) {
  return __uint_as_float(((unsigned)(unsigned short)h) << 16);
}
static __device__ __forceinline__ float sigm(float x) {
  return 1.0f / (1.0f + __expf(-x));
}
static __device__ __forceinline__ float tanh_(float x) {
  return 2.0f / (1.0f + __expf(-2.0f * x)) - 1.0f;
}

// ---- weight repack: interleaved hi|lo per 8-group --------------------------
__global__ void pack_w_kernel(const float* __restrict__ kern,
                              const float* __restrict__ rec,
                              short* __restrict__ Wp) {
  const int col = blockIdx.x;   // 0..1023
  const int k   = threadIdx.x;  // 0..319
  const float w = (k < FIN) ? kern[k * ZDIM + col] : rec[(k - FIN) * ZDIM + col];
  const short hi = f2bf(w);
  const int base = col * WCOL + (k >> 3) * 16 + (k & 7);
  Wp[base]     = hi;
  Wp[base + 8] = f2bf(w - bf2f(hi));
}

__global__ void pack_dw_kernel(const float* __restrict__ dw,
                               short* __restrict__ Dp) {
  const int col = blockIdx.x;   // 0..79 (>=65 zero-padded)
  const int k   = threadIdx.x;  // 0..255
  const float w = (col < OCOLS) ? dw[k * OCOLS + col] : 0.0f;
  const short hi = f2bf(w);
  const int base = col * DCOL + (k >> 3) * 16 + (k & 7);
  Dp[base]     = hi;
  Dp[base + 8] = f2bf(w - bf2f(hi));
}

// ---- persistent LSTM + autoregressive kernel -------------------------------
// 64 blocks x 512 thr; block owns 64 batch rows for all 88 steps.
// wave wv owns u in [wv*32, wv*32+32) for ALL 4 gates (reg-only gate fusion),
// and all 4 row-tiles (m=0..3) -> 12 dependent MFMAs per 32B W load-pair.
__global__ __launch_bounds__(NTHR, 2) void lstm_ar_kernel(
    const float* __restrict__ inputs, const float* __restrict__ bias,
    const float* __restrict__ dense_b, const short* __restrict__ Wp,
    const short* __restrict__ Dp, float* __restrict__ out) {
  __shared__ short Ah[BR * ASTR];   // A = [x(0:64) | h(64:320)] bf16 hi
  __shared__ short Al[BR * ASTR];   // bf16 lo residual

  const int tid  = (int)threadIdx.x;
  const int wv   = tid >> 6;        // wave 0..7
  const int lane = tid & 63;
  const int lrow = lane >> 4;       // k-group 0..3
  const int lcol = lane & 15;
  const int b0   = (int)blockIdx.x * BR;

  float bz[2][4];
#pragma unroll
  for (int ut = 0; ut < 2; ++ut)
#pragma unroll
    for (int g = 0; g < 4; ++g)
      bz[ut][g] = bias[g * UDIM + wv * 32 + ut * 16 + lcol];
  float dbz[5];
#pragma unroll
  for (int ct = 0; ct < 5; ++ct) {
    const int col = ct * 16 + lcol;
    dbz[ct] = (col < OCOLS) ? dense_b[col] : 0.0f;
  }

  // cell state, MFMA C/D layout: row = m*16 + lrow*4 + q, u = wv*32 + ut*16 + lcol
  float cst[MT][2][4] = {{{0.0f}}};

  // stage x_t: 64 rows x 16 float4 = 1024 float4, 2 per thread
  auto stage_x = [&](int t) {
#pragma unroll
    for (int i = 0; i < 2; ++i) {
      const int idx = tid * 2 + i;
      const int r   = idx >> 4;
      const int c4  = (idx & 15) << 2;
      const float4 v = *reinterpret_cast<const float4*>(
          inputs + (size_t)(b0 + r) * (TWARM * FIN) + (size_t)t * FIN + c4);
      s16x4 hi, lo;
      hi[0] = f2bf(v.x); lo[0] = f2bf(v.x - bf2f(hi[0]));
      hi[1] = f2bf(v.y); lo[1] = f2bf(v.y - bf2f(hi[1]));
      hi[2] = f2bf(v.z); lo[2] = f2bf(v.z - bf2f(hi[2]));
      hi[3] = f2bf(v.w); lo[3] = f2bf(v.w - bf2f(hi[3]));
      *reinterpret_cast<s16x4*>(&Ah[r * ASTR + c4]) = hi;
      *reinterpret_cast<s16x4*>(&Al[r * ASTR + c4]) = lo;
    }
  };

  auto lstm_step = [&]() {
    f32x4 acc[MT][2][4];
#pragma unroll
    for (int m = 0; m < MT; ++m)
#pragma unroll
      for (int ut = 0; ut < 2; ++ut)
#pragma unroll
        for (int g = 0; g < 4; ++g) {
          acc[m][ut][g][0] = bz[ut][g]; acc[m][ut][g][1] = bz[ut][g];
          acc[m][ut][g][2] = bz[ut][g]; acc[m][ut][g][3] = bz[ut][g];
        }
#pragma unroll
    for (int kt = 0; kt < 10; ++kt) {
      const int k0 = kt * 32;
      bf16x8 ah[MT], al[MT];
#pragma unroll
      for (int m = 0; m < MT; ++m) {
        const int aoff = (m * 16 + lcol) * ASTR + k0 + lrow * 8;
        ah[m] = *reinterpret_cast<const bf16x8*>(&Ah[aoff]);
        al[m] = *reinterpret_cast<const bf16x8*>(&Al[aoff]);
      }
#pragma unroll
      for (int ct = 0; ct < 8; ++ct) {
        const int g = ct >> 1, ut = ct & 1;
        const int zcol = g * UDIM + wv * 32 + ut * 16 + lcol;
        const int woff = zcol * WCOL + (kt * 4 + lrow) * 16;
        const bf16x8 bh = *reinterpret_cast<const bf16x8*>(Wp + woff);
#if PRECISE
        const bf16x8 bl = *reinterpret_cast<const bf16x8*>(Wp + woff + 8);
#endif
#pragma unroll
        for (int m = 0; m < MT; ++m) {
          acc[m][ut][g] = __builtin_amdgcn_mfma_f32_16x16x32_bf16(ah[m], bh, acc[m][ut][g], 0, 0, 0);
#if PRECISE
          acc[m][ut][g] = __builtin_amdgcn_mfma_f32_16x16x32_bf16(al[m], bh, acc[m][ut][g], 0, 0, 0);
          acc[m][ut][g] = __builtin_amdgcn_mfma_f32_16x16x32_bf16(ah[m], bl, acc[m][ut][g], 0, 0, 0);
#endif
        }
      }
    }
    __syncthreads();  // all waves done reading A before h is overwritten
#pragma unroll
    for (int m = 0; m < MT; ++m)
#pragma unroll
      for (int ut = 0; ut < 2; ++ut)
#pragma unroll
        for (int q = 0; q < 4; ++q) {
          const float iv = sigm(acc[m][ut][0][q]);
          const float fv = sigm(acc[m][ut][1][q]);
          const float gv = tanh_(acc[m][ut][2][q]);
          const float ov = sigm(acc[m][ut][3][q]);
          const float c  = fv * cst[m][ut][q] + iv * gv;
          cst[m][ut][q]  = c;
          const float h  = ov * tanh_(c);
          const int row  = m * 16 + lrow * 4 + q;
          const int u    = wv * 32 + ut * 16 + lcol;
          const short hi = f2bf(h);
          Ah[row * ASTR + FIN + u] = hi;
          Al[row * ASTR + FIN + u] = f2bf(h - bf2f(hi));
        }
  };

  // init: zero A (h0 = 0), then stage x_0
  for (int i = tid; i < BR * ASTR; i += NTHR) { Ah[i] = 0; Al[i] = 0; }
  __syncthreads();
  stage_x(0);
  __syncthreads();

  // ---- warm phase ----
#pragma unroll 1
  for (int t = 0; t < TWARM; ++t) {
    lstm_step();
    if (t + 1 < TWARM) stage_x(t + 1);   // x region disjoint from h region
    __syncthreads();
  }

  // ---- autoregressive phase ----
#pragma unroll 1
  for (int s = 0; s < OSTEPS; ++s) {
    // dense: pred = h @ Dw + db on waves 0..3 (wave m handles row-tile m).
    // reads A k=64..319, writes A k=0..63 (disjoint) + out column.
    if (wv < MT) {
      const int m = wv;
      f32x4 p[5];
#pragma unroll
      for (int ct = 0; ct < 5; ++ct) {
        p[ct][0] = dbz[ct]; p[ct][1] = dbz[ct]; p[ct][2] = dbz[ct]; p[ct][3] = dbz[ct];
      }
#pragma unroll
      for (int kt = 0; kt < 8; ++kt) {
        const int k0   = FIN + kt * 32;
        const int aoff = (m * 16 + lcol) * ASTR + k0 + lrow * 8;
        const bf16x8 ah = *reinterpret_cast<const bf16x8*>(&Ah[aoff]);
#if PRECISE
        const bf16x8 al = *reinterpret_cast<const bf16x8*>(&Al[aoff]);
#endif
#pragma unroll
        for (int ct = 0; ct < 5; ++ct) {
          const int doff = (ct * 16 + lcol) * DCOL + (kt * 4 + lrow) * 16;
          const bf16x8 bh = *reinterpret_cast<const bf16x8*>(Dp + doff);
          p[ct] = __builtin_amdgcn_mfma_f32_16x16x32_bf16(ah, bh, p[ct], 0, 0, 0);
#if PRECISE
          const bf16x8 bl = *reinterpret_cast<const bf16x8*>(Dp + doff + 8);
          p[ct] = __builtin_amdgcn_mfma_f32_16x16x32_bf16(al, bh, p[ct], 0, 0, 0);
          p[ct] = __builtin_amdgcn_mfma_f32_16x16x32_bf16(ah, bl, p[ct], 0, 0, 0);
#endif
        }
      }
      // x_next = pred[:, 0:64] -> A staging (k = col)
#pragma unroll
      for (int ct = 0; ct < 4; ++ct)
#pragma unroll
        for (int q = 0; q < 4; ++q) {
          const float v  = p[ct][q];
          const int row  = m * 16 + lrow * 4 + q;
          const int col  = ct * 16 + lcol;
          const short hi = f2bf(v);
          Ah[row * ASTR + col] = hi;
          Al[row * ASTR + col] = f2bf(v - bf2f(hi));
        }
      // out[:, s] = pred[:, 64]  (col-tile 4, lcol==0)
      if (lcol == 0) {
#pragma unroll
        for (int q = 0; q < 4; ++q)
          out[(size_t)(b0 + m * 16 + lrow * 4 + q) * OSTEPS + s] = p[4][q];
      }
    }
    __syncthreads();
    if (s + 1 < OSTEPS) {
      lstm_step();
      __syncthreads();
    }
  }
}

// ---- launch ---------------------------------------------------------------
extern "C" void kernel_launch(void* const* d_in, const int* in_sizes, int n_in,
                              void* d_out, int out_size, void* d_ws, size_t ws_size,
                              hipStream_t stream) {
  (void)in_sizes; (void)n_in; (void)out_size; (void)ws_size;
  const float* inputs = (const float*)d_in[0];
  const float* kern   = (const float*)d_in[1];
  const float* rec    = (const float*)d_in[2];
  const float* bias   = (const float*)d_in[3];
  const float* dw     = (const float*)d_in[4];
  const float* db     = (const float*)d_in[5];
  float* out = (float*)d_out;

  short* Wp = (short*)d_ws;              // 1024*640 shorts = 1.31 MB
  short* Dp = Wp + ZDIM * WCOL;          // 80*512 shorts   = 82 KB

  hipLaunchKernelGGL(pack_w_kernel,  dim3(ZDIM),  dim3(KDIM), 0, stream, kern, rec, Wp);
  hipLaunchKernelGGL(pack_dw_kernel, dim3(OCPAD), dim3(UDIM), 0, stream, dw, Dp);
  hipLaunchKernelGGL(lstm_ar_kernel, dim3(NB), dim3(NTHR), 0, stream,
                     inputs, bias, db, Wp, Dp, out);
}

// Round 3
// 5192.313 us; speedup vs baseline: 1.1413x; 1.1413x over previous
//
#include <hip/hip_runtime.h>

// ---- problem constants -----------------------------------------------------
#define PRECISE 1        // 1: bf16 hi/lo split (fp32-accurate), 0: plain bf16
#define BTOT   4096      // batch
#define TWARM  64        // warm timesteps
#define FIN    64        // input features
#define UDIM   256       // hidden units
#define ZDIM   1024      // 4*U gate pre-activations
#define KDIM   320       // FIN + UDIM (concat [x|h] @ [K;R])
#define OSTEPS 24
#define OCOLS  65        // dense out dim (F+1)
#define OCPAD  80        // padded to 5 col-tiles of 16
#define BR     32        // batch rows per block (R3: back to 32, 128 blocks)
#define NB     (BTOT / BR)   // 128 blocks
#define ASTR   344       // LDS A row stride in bf16 (320 + 24 pad)
#define NTHR   512       // 8 waves
#define MT     (BR / 16) // 2 row-tiles per wave

// R3 W layout, pipeline-friendly: short index =
//   (kt*8 + wv)*8192 + ct*1024 + lcol*64 + lrow*16 + hl*8 + j
// -> per (wave, kt): 16 contiguous-2KB loads (8 ct x hi/lo 16B each).
#define DCOL   512       // dense W: per col 512 shorts, hi8|lo8 interleave

typedef short bf16x8 __attribute__((ext_vector_type(8)));
typedef short s16x4  __attribute__((ext_vector_type(4)));
typedef float f32x4  __attribute__((ext_vector_type(4)));

static __device__ __forceinline__ short f2bf(float x) {  // RNE f32 -> bf16 bits
  unsigned u = __float_as_uint(x);
  return (short)((u + 0x7fffu + ((u >> 16) & 1u)) >> 16);
}
static __device__ __forceinline__ float bf2f(short h) {
  return __uint_as_float(((unsigned)(unsigned short)h) << 16);
}
static __device__ __forceinline__ float sigm(float x) {
  return 1.0f / (1.0f + __expf(-x));
}
static __device__ __forceinline__ float tanh_(float x) {
  return 2.0f / (1.0f + __expf(-2.0f * x)) - 1.0f;
}

// ---- weight repack into the pipelined layout --------------------------------
__global__ void pack_w_kernel(const float* __restrict__ kern,
                              const float* __restrict__ rec,
                              short* __restrict__ Wp) {
  const int col = blockIdx.x;   // 0..1023  (zcol)
  const int k   = threadIdx.x;  // 0..319
  const float w = (k < FIN) ? kern[k * ZDIM + col] : rec[(k - FIN) * ZDIM + col];
  const short hi = f2bf(w);
  const int g    = col >> 8;
  const int wv   = (col >> 5) & 7;
  const int ut   = (col >> 4) & 1;
  const int lcol = col & 15;
  const int ct   = g * 2 + ut;
  const int kt   = k >> 5;
  const int lrow = (k >> 3) & 3;
  const int j    = k & 7;
  const int base = (kt * 8 + wv) * 8192 + ct * 1024 + lcol * 64 + lrow * 16 + j;
  Wp[base]     = hi;
  Wp[base + 8] = f2bf(w - bf2f(hi));
}

__global__ void pack_dw_kernel(const float* __restrict__ dw,
                               short* __restrict__ Dp) {
  const int col = blockIdx.x;   // 0..79 (>=65 zero-padded)
  const int k   = threadIdx.x;  // 0..255
  const float w = (col < OCOLS) ? dw[k * OCOLS + col] : 0.0f;
  const short hi = f2bf(w);
  const int base = col * DCOL + (k >> 3) * 16 + (k & 7);
  Dp[base]     = hi;
  Dp[base + 8] = f2bf(w - bf2f(hi));
}

// ---- persistent LSTM + autoregressive kernel -------------------------------
// 128 blocks x 512 thr; block owns 32 batch rows for all 88 steps.
// wave wv owns u in [wv*32, wv*32+32) for ALL 4 gates; acc = 64 AGPRs,
// leaving ~128 VGPRs for a 2-deep register pipeline on W (16 loads in flight).
__global__ __launch_bounds__(NTHR, 2) void lstm_ar_kernel(
    const float* __restrict__ inputs, const float* __restrict__ bias,
    const float* __restrict__ dense_b, const short* __restrict__ Wp,
    const short* __restrict__ Dp, float* __restrict__ out) {
  __shared__ short Ah[BR * ASTR];   // A = [x(0:64) | h(64:320)] bf16 hi
  __shared__ short Al[BR * ASTR];   // bf16 lo residual

  const int tid  = (int)threadIdx.x;
  const int wv   = tid >> 6;        // wave 0..7
  const int lane = tid & 63;
  const int lrow = lane >> 4;       // k-group 0..3
  const int lcol = lane & 15;
  const int b0   = (int)blockIdx.x * BR;

  float bz[2][4];
#pragma unroll
  for (int ut = 0; ut < 2; ++ut)
#pragma unroll
    for (int g = 0; g < 4; ++g)
      bz[ut][g] = bias[g * UDIM + wv * 32 + ut * 16 + lcol];
  float dbz[5];
#pragma unroll
  for (int ct = 0; ct < 5; ++ct) {
    const int col = ct * 16 + lcol;
    dbz[ct] = (col < OCOLS) ? dense_b[col] : 0.0f;
  }

  // per-lane W base: loads for (kt,ct) are at wlane + kt*65536 + ct*1024 (+8 lo)
  const short* wlane = Wp + wv * 8192 + lcol * 64 + lrow * 16;

  // cell state, MFMA C/D layout: row = m*16 + lrow*4 + q, u = wv*32 + ut*16 + lcol
  float cst[MT][2][4] = {{{0.0f}}};

  // stage x_t: 32 rows x 16 float4 = 512 float4, one per thread
  auto stage_x = [&](int t) {
    const int r  = tid >> 4;
    const int c4 = (tid & 15) << 2;
    const float4 v = *reinterpret_cast<const float4*>(
        inputs + (size_t)(b0 + r) * (TWARM * FIN) + (size_t)t * FIN + c4);
    s16x4 hi, lo;
    hi[0] = f2bf(v.x); lo[0] = f2bf(v.x - bf2f(hi[0]));
    hi[1] = f2bf(v.y); lo[1] = f2bf(v.y - bf2f(hi[1]));
    hi[2] = f2bf(v.z); lo[2] = f2bf(v.z - bf2f(hi[2]));
    hi[3] = f2bf(v.w); lo[3] = f2bf(v.w - bf2f(hi[3]));
    *reinterpret_cast<s16x4*>(&Ah[r * ASTR + c4]) = hi;
    *reinterpret_cast<s16x4*>(&Al[r * ASTR + c4]) = lo;
  };

  auto lstm_step = [&]() {
    f32x4 acc[MT][2][4];
#pragma unroll
    for (int m = 0; m < MT; ++m)
#pragma unroll
      for (int ut = 0; ut < 2; ++ut)
#pragma unroll
        for (int g = 0; g < 4; ++g) {
          acc[m][ut][g][0] = bz[ut][g]; acc[m][ut][g][1] = bz[ut][g];
          acc[m][ut][g][2] = bz[ut][g]; acc[m][ut][g][3] = bz[ut][g];
        }

    // ---- 2-deep register pipeline over kt: W[kt+1] issued before W[kt] used
    bf16x8 wb[2][8][2];   // [buf][ct][hi/lo]; buf index is unroll-static
#pragma unroll
    for (int ct = 0; ct < 8; ++ct) {
      wb[0][ct][0] = *reinterpret_cast<const bf16x8*>(wlane + ct * 1024);
      wb[0][ct][1] = *reinterpret_cast<const bf16x8*>(wlane + ct * 1024 + 8);
    }
#pragma unroll
    for (int kt = 0; kt < 10; ++kt) {
      const int cur = kt & 1;
      const int nxt = cur ^ 1;
      if (kt < 9) {
        const short* wnext = wlane + (kt + 1) * 65536;
#pragma unroll
        for (int ct = 0; ct < 8; ++ct) {
          wb[nxt][ct][0] = *reinterpret_cast<const bf16x8*>(wnext + ct * 1024);
          wb[nxt][ct][1] = *reinterpret_cast<const bf16x8*>(wnext + ct * 1024 + 8);
        }
      }
      const int k0 = kt * 32;
      bf16x8 ah[MT], al[MT];
#pragma unroll
      for (int m = 0; m < MT; ++m) {
        const int aoff = (m * 16 + lcol) * ASTR + k0 + lrow * 8;
        ah[m] = *reinterpret_cast<const bf16x8*>(&Ah[aoff]);
        al[m] = *reinterpret_cast<const bf16x8*>(&Al[aoff]);
      }
#pragma unroll
      for (int ct = 0; ct < 8; ++ct) {
        const int g = ct >> 1, ut = ct & 1;
        const bf16x8 bh = wb[cur][ct][0];
#if PRECISE
        const bf16x8 bl = wb[cur][ct][1];
#endif
#pragma unroll
        for (int m = 0; m < MT; ++m) {
          acc[m][ut][g] = __builtin_amdgcn_mfma_f32_16x16x32_bf16(ah[m], bh, acc[m][ut][g], 0, 0, 0);
#if PRECISE
          acc[m][ut][g] = __builtin_amdgcn_mfma_f32_16x16x32_bf16(al[m], bh, acc[m][ut][g], 0, 0, 0);
          acc[m][ut][g] = __builtin_amdgcn_mfma_f32_16x16x32_bf16(ah[m], bl, acc[m][ut][g], 0, 0, 0);
#endif
        }
      }
    }
    __syncthreads();  // all waves done reading A before h is overwritten
#pragma unroll
    for (int m = 0; m < MT; ++m)
#pragma unroll
      for (int ut = 0; ut < 2; ++ut)
#pragma unroll
        for (int q = 0; q < 4; ++q) {
          const float iv = sigm(acc[m][ut][0][q]);
          const float fv = sigm(acc[m][ut][1][q]);
          const float gv = tanh_(acc[m][ut][2][q]);
          const float ov = sigm(acc[m][ut][3][q]);
          const float c  = fv * cst[m][ut][q] + iv * gv;
          cst[m][ut][q]  = c;
          const float h  = ov * tanh_(c);
          const int row  = m * 16 + lrow * 4 + q;
          const int u    = wv * 32 + ut * 16 + lcol;
          const short hi = f2bf(h);
          Ah[row * ASTR + FIN + u] = hi;
          Al[row * ASTR + FIN + u] = f2bf(h - bf2f(hi));
        }
  };

  // init: zero A (h0 = 0), then stage x_0
  for (int i = tid; i < BR * ASTR; i += NTHR) { Ah[i] = 0; Al[i] = 0; }
  __syncthreads();
  stage_x(0);
  __syncthreads();

  // ---- warm phase ----
#pragma unroll 1
  for (int t = 0; t < TWARM; ++t) {
    lstm_step();
    if (t + 1 < TWARM) stage_x(t + 1);   // x region disjoint from h region
    __syncthreads();
  }

  // ---- autoregressive phase ----
#pragma unroll 1
  for (int s = 0; s < OSTEPS; ++s) {
    // dense: pred = h @ Dw + db on waves 0,1 (wave m handles row-tile m).
    // reads A k=64..319, writes A k=0..63 (disjoint) + out column.
    if (wv < MT) {
      const int m = wv;
      f32x4 p[5];
#pragma unroll
      for (int ct = 0; ct < 5; ++ct) {
        p[ct][0] = dbz[ct]; p[ct][1] = dbz[ct]; p[ct][2] = dbz[ct]; p[ct][3] = dbz[ct];
      }
#pragma unroll
      for (int kt = 0; kt < 8; ++kt) {
        const int k0   = FIN + kt * 32;
        const int aoff = (m * 16 + lcol) * ASTR + k0 + lrow * 8;
        const bf16x8 ah = *reinterpret_cast<const bf16x8*>(&Ah[aoff]);
#if PRECISE
        const bf16x8 al = *reinterpret_cast<const bf16x8*>(&Al[aoff]);
#endif
#pragma unroll
        for (int ct = 0; ct < 5; ++ct) {
          const int doff = (ct * 16 + lcol) * DCOL + (kt * 4 + lrow) * 16;
          const bf16x8 bh = *reinterpret_cast<const bf16x8*>(Dp + doff);
          p[ct] = __builtin_amdgcn_mfma_f32_16x16x32_bf16(ah, bh, p[ct], 0, 0, 0);
#if PRECISE
          const bf16x8 bl = *reinterpret_cast<const bf16x8*>(Dp + doff + 8);
          p[ct] = __builtin_amdgcn_mfma_f32_16x16x32_bf16(al, bh, p[ct], 0, 0, 0);
          p[ct] = __builtin_amdgcn_mfma_f32_16x16x32_bf16(ah, bl, p[ct], 0, 0, 0);
#endif
        }
      }
      // x_next = pred[:, 0:64] -> A staging (k = col)
#pragma unroll
      for (int ct = 0; ct < 4; ++ct)
#pragma unroll
        for (int q = 0; q < 4; ++q) {
          const float v  = p[ct][q];
          const int row  = m * 16 + lrow * 4 + q;
          const int col  = ct * 16 + lcol;
          const short hi = f2bf(v);
          Ah[row * ASTR + col] = hi;
          Al[row * ASTR + col] = f2bf(v - bf2f(hi));
        }
      // out[:, s] = pred[:, 64]  (col-tile 4, lcol==0)
      if (lcol == 0) {
#pragma unroll
        for (int q = 0; q < 4; ++q)
          out[(size_t)(b0 + m * 16 + lrow * 4 + q) * OSTEPS + s] = p[4][q];
      }
    }
    __syncthreads();
    if (s + 1 < OSTEPS) {
      lstm_step();
      __syncthreads();
    }
  }
}

// ---- launch ---------------------------------------------------------------
extern "C" void kernel_launch(void* const* d_in, const int* in_sizes, int n_in,
                              void* d_out, int out_size, void* d_ws, size_t ws_size,
                              hipStream_t stream) {
  (void)in_sizes; (void)n_in; (void)out_size; (void)ws_size;
  const float* inputs = (const float*)d_in[0];
  const float* kern   = (const float*)d_in[1];
  const float* rec    = (const float*)d_in[2];
  const float* bias   = (const float*)d_in[3];
  const float* dw     = (const float*)d_in[4];
  const float* db     = (const float*)d_in[5];
  float* out = (float*)d_out;

  short* Wp = (short*)d_ws;              // 10*8*8192 shorts = 1.31 MB
  short* Dp = Wp + 10 * 8 * 8192;        // 80*512 shorts   = 82 KB

  hipLaunchKernelGGL(pack_w_kernel,  dim3(ZDIM),  dim3(KDIM), 0, stream, kern, rec, Wp);
  hipLaunchKernelGGL(pack_dw_kernel, dim3(OCPAD), dim3(UDIM), 0, stream, dw, Dp);
  hipLaunchKernelGGL(lstm_ar_kernel, dim3(NB), dim3(NTHR), 0, stream,
                     inputs, bias, db, Wp, Dp, out);
}

// Round 5
// 4207.936 us; speedup vs baseline: 1.4083x; 1.2339x over previous
//
#include <hip/hip_runtime.h>

// ---- problem constants -----------------------------------------------------
#define BTOT   4096      // batch
#define TWARM  64        // warm timesteps
#define FIN    64        // input features
#define UDIM   256       // hidden units
#define ZDIM   1024      // 4*U gate pre-activations
#define KDIM   320       // FIN + UDIM
#define OSTEPS 24
#define OCOLS  65        // dense out dim (F+1)
#define BR     16        // batch rows per block -> 256 blocks, 1 per CU
#define NB     (BTOT / BR)
#define ASTR   344       // LDS A row stride in bf16 (320 + 24 pad)
#define NTHR   1024      // 16 waves
// R4: W is REGISTER-STATIONARY. Wave wv owns u in [wv*16, wv*16+16):
//   z-cols {g*256 + wv*16 + lcol}, W slice = 4g x 10kt x (hi+lo) = 320 VGPR/lane.
// Wp layout: ((wv*4+g)*10+kt)*1024 + lcol*64 + lrow*16 + hl*8 + j
// Dp layout: ((ct*8+kt)*1024)      + lcol*64 + lrow*16 + hl*8 + j  (ct 0..4)

typedef short bf16x8 __attribute__((ext_vector_type(8)));
typedef short s16x4  __attribute__((ext_vector_type(4)));
typedef float f32x4  __attribute__((ext_vector_type(4)));

static __device__ __forceinline__ short f2bf(float x) {  // RNE f32 -> bf16 bits
  unsigned u = __float_as_uint(x);
  return (short)((u + 0x7fffu + ((u >> 16) & 1u)) >> 16);
}
static __device__ __forceinline__ float bf2f(short h) {
  return __uint_as_float(((unsigned)(unsigned short)h) << 16);
}
static __device__ __forceinline__ float sigm(float x) {
  return 1.0f / (1.0f + __expf(-x));
}
static __device__ __forceinline__ float tanh_(float x) {
  return 2.0f / (1.0f + __expf(-2.0f * x)) - 1.0f;
}

// ---- weight repack into per-wave register-fragment order --------------------
__global__ void pack_w_kernel(const float* __restrict__ kern,
                              const float* __restrict__ rec,
                              short* __restrict__ Wp) {
  const int col = blockIdx.x;   // 0..1023 (zcol)
  const int k   = threadIdx.x;  // 0..319
  const float w = (k < FIN) ? kern[k * ZDIM + col] : rec[(k - FIN) * ZDIM + col];
  const short hi = f2bf(w);
  const int g    = col >> 8;
  const int wvp  = (col >> 4) & 15;
  const int lc   = col & 15;
  const int kt   = k >> 5;
  const int lr   = (k >> 3) & 3;
  const int j    = k & 7;
  const int base = ((wvp * 4 + g) * 10 + kt) * 1024 + lc * 64 + lr * 16 + j;
  Wp[base]     = hi;
  Wp[base + 8] = f2bf(w - bf2f(hi));
}

__global__ void pack_dw_kernel(const float* __restrict__ dw,
                               short* __restrict__ Dp) {
  const int col = blockIdx.x;   // 0..79 (>=65 zero-padded)
  const int k   = threadIdx.x;  // 0..255
  const float w = (col < OCOLS) ? dw[k * OCOLS + col] : 0.0f;
  const short hi = f2bf(w);
  const int ct = col >> 4;
  const int lc = col & 15;
  const int kt = k >> 5;
  const int lr = (k >> 3) & 3;
  const int j  = k & 7;
  const int base = (ct * 8 + kt) * 1024 + lc * 64 + lr * 16 + j;
  Dp[base]     = hi;
  Dp[base + 8] = f2bf(w - bf2f(hi));
}

// ---- persistent LSTM + AR kernel: W lives in registers ----------------------
__global__ __launch_bounds__(NTHR, 4) void lstm_ar_kernel(
    const float* __restrict__ inputs, const float* __restrict__ bias,
    const float* __restrict__ dense_b, const short* __restrict__ Wp,
    const short* __restrict__ Dp, float* __restrict__ out) {
  __shared__ short Ah[BR * ASTR];   // A = [x(0:64) | h(64:320)] bf16 hi
  __shared__ short Al[BR * ASTR];   // bf16 lo residual

  const int tid  = (int)threadIdx.x;
  const int wv   = tid >> 6;        // wave 0..15
  const int lane = tid & 63;
  const int lrow = lane >> 4;       // k-group 0..3
  const int lcol = lane & 15;
  const int b0   = (int)blockIdx.x * BR;
  const int laneoff = lcol * 64 + lrow * 16;

  // ---- load stationary W: 80 x bf16x8 = 320 VGPRs, once, reused 88 steps ----
  bf16x8 wh[4][10], wl[4][10];
#pragma unroll
  for (int g = 0; g < 4; ++g)
#pragma unroll
    for (int kt = 0; kt < 10; ++kt) {
      const short* p = Wp + ((wv * 4 + g) * 10 + kt) * 1024 + laneoff;
      wh[g][kt] = *reinterpret_cast<const bf16x8*>(p);
      wl[g][kt] = *reinterpret_cast<const bf16x8*>(p + 8);
    }
  // dense weights stationary on waves 0..4 (ct = wv): 16 x bf16x8 = 64 VGPRs
  bf16x8 dh[8], dl[8];
  float dbz = 0.0f;
  if (wv < 5) {
#pragma unroll
    for (int kt = 0; kt < 8; ++kt) {
      const short* p = Dp + (wv * 8 + kt) * 1024 + laneoff;
      dh[kt] = *reinterpret_cast<const bf16x8*>(p);
      dl[kt] = *reinterpret_cast<const bf16x8*>(p + 8);
    }
    const int col = wv * 16 + lcol;
    dbz = (col < OCOLS) ? dense_b[col] : 0.0f;
  }

  float bz[4];
#pragma unroll
  for (int g = 0; g < 4; ++g)
    bz[g] = bias[g * UDIM + wv * 16 + lcol];

  // cell state, C/D layout: row = lrow*4+q, u = wv*16+lcol
  f32x4 cst; cst[0] = 0.f; cst[1] = 0.f; cst[2] = 0.f; cst[3] = 0.f;

  // stage x_t: 16 rows x 16 float4 = 256 loads (threads 0..255)
  auto stage_x = [&](int t) {
    if (tid < 256) {
      const int r  = tid >> 4;
      const int c4 = (tid & 15) << 2;
      const float4 v = *reinterpret_cast<const float4*>(
          inputs + (size_t)(b0 + r) * (TWARM * FIN) + (size_t)t * FIN + c4);
      s16x4 hi, lo;
      hi[0] = f2bf(v.x); lo[0] = f2bf(v.x - bf2f(hi[0]));
      hi[1] = f2bf(v.y); lo[1] = f2bf(v.y - bf2f(hi[1]));
      hi[2] = f2bf(v.z); lo[2] = f2bf(v.z - bf2f(hi[2]));
      hi[3] = f2bf(v.w); lo[3] = f2bf(v.w - bf2f(hi[3]));
      *reinterpret_cast<s16x4*>(&Ah[r * ASTR + c4]) = hi;
      *reinterpret_cast<s16x4*>(&Al[r * ASTR + c4]) = lo;
    }
  };

  // one LSTM step: zero global loads. 20 ds_read + 120 MFMA per wave.
  auto lstm_step = [&]() {
    f32x4 acc[4];
#pragma unroll
    for (int g = 0; g < 4; ++g) {
      acc[g][0] = bz[g]; acc[g][1] = bz[g]; acc[g][2] = bz[g]; acc[g][3] = bz[g];
    }
#pragma unroll
    for (int kt = 0; kt < 10; ++kt) {
      const int aoff = lcol * ASTR + kt * 32 + lrow * 8;
      const bf16x8 ah = *reinterpret_cast<const bf16x8*>(&Ah[aoff]);
      const bf16x8 al = *reinterpret_cast<const bf16x8*>(&Al[aoff]);
#pragma unroll
      for (int g = 0; g < 4; ++g) {
        acc[g] = __builtin_amdgcn_mfma_f32_16x16x32_bf16(ah, wh[g][kt], acc[g], 0, 0, 0);
        acc[g] = __builtin_amdgcn_mfma_f32_16x16x32_bf16(al, wh[g][kt], acc[g], 0, 0, 0);
        acc[g] = __builtin_amdgcn_mfma_f32_16x16x32_bf16(ah, wl[g][kt], acc[g], 0, 0, 0);
      }
    }
    __syncthreads();  // all waves done reading A before h is overwritten
#pragma unroll
    for (int q = 0; q < 4; ++q) {
      const float iv = sigm(acc[0][q]);
      const float fv = sigm(acc[1][q]);
      const float gv = tanh_(acc[2][q]);
      const float ov = sigm(acc[3][q]);
      const float c  = fv * cst[q] + iv * gv;
      cst[q] = c;
      const float h  = ov * tanh_(c);
      const int row  = lrow * 4 + q;
      const int u    = wv * 16 + lcol;
      const short hi = f2bf(h);
      Ah[row * ASTR + FIN + u] = hi;
      Al[row * ASTR + FIN + u] = f2bf(h - bf2f(hi));
    }
  };

  // init: zero A (h0 = 0), stage x_0
  for (int i = tid; i < BR * ASTR; i += NTHR) { Ah[i] = 0; Al[i] = 0; }
  __syncthreads();
  stage_x(0);
  __syncthreads();

  // ---- warm phase ----
#pragma unroll 1
  for (int t = 0; t < TWARM; ++t) {
    lstm_step();
    if (t + 1 < TWARM) stage_x(t + 1);   // x region disjoint from h region
    __syncthreads();
  }

  // ---- autoregressive phase ----
#pragma unroll 1
  for (int s = 0; s < OSTEPS; ++s) {
    // dense on waves 0..4 (ct = wv): reads A h-region, writes x-region / out
    if (wv < 5) {
      f32x4 p; p[0] = dbz; p[1] = dbz; p[2] = dbz; p[3] = dbz;
#pragma unroll
      for (int kt = 0; kt < 8; ++kt) {
        const int aoff = lcol * ASTR + FIN + kt * 32 + lrow * 8;
        const bf16x8 ah = *reinterpret_cast<const bf16x8*>(&Ah[aoff]);
        const bf16x8 al = *reinterpret_cast<const bf16x8*>(&Al[aoff]);
        p = __builtin_amdgcn_mfma_f32_16x16x32_bf16(ah, dh[kt], p, 0, 0, 0);
        p = __builtin_amdgcn_mfma_f32_16x16x32_bf16(al, dh[kt], p, 0, 0, 0);
        p = __builtin_amdgcn_mfma_f32_16x16x32_bf16(ah, dl[kt], p, 0, 0, 0);
      }
      if (wv < 4) {       // x_next = pred[:, 0:64]
#pragma unroll
        for (int q = 0; q < 4; ++q) {
          const float v  = p[q];
          const int row  = lrow * 4 + q;
          const int col  = wv * 16 + lcol;
          const short hi = f2bf(v);
          Ah[row * ASTR + col] = hi;
          Al[row * ASTR + col] = f2bf(v - bf2f(hi));
        }
      } else if (lcol == 0) {  // col 64 = the output column
#pragma unroll
        for (int q = 0; q < 4; ++q)
          out[(size_t)(b0 + lrow * 4 + q) * OSTEPS + s] = p[q];
      }
    }
    __syncthreads();
    if (s + 1 < OSTEPS) {
      lstm_step();
      __syncthreads();
    }
  }
}

// ---- launch ---------------------------------------------------------------
extern "C" void kernel_launch(void* const* d_in, const int* in_sizes, int n_in,
                              void* d_out, int out_size, void* d_ws, size_t ws_size,
                              hipStream_t stream) {
  (void)in_sizes; (void)n_in; (void)out_size; (void)ws_size;
  const float* inputs = (const float*)d_in[0];
  const float* kern   = (const float*)d_in[1];
  const float* rec    = (const float*)d_in[2];
  const float* bias   = (const float*)d_in[3];
  const float* dw     = (const float*)d_in[4];
  const float* db     = (const float*)d_in[5];
  float* out = (float*)d_out;

  short* Wp = (short*)d_ws;              // 16*4*10*1024 shorts = 1.31 MB
  short* Dp = Wp + 16 * 4 * 10 * 1024;   // 5*8*1024 shorts    = 82 KB

  hipLaunchKernelGGL(pack_w_kernel,  dim3(ZDIM), dim3(KDIM), 0, stream, kern, rec, Wp);
  hipLaunchKernelGGL(pack_dw_kernel, dim3(80),   dim3(UDIM), 0, stream, dw, Dp);
  hipLaunchKernelGGL(lstm_ar_kernel, dim3(NB), dim3(NTHR), 0, stream,
                     inputs, bias, db, Wp, Dp, out);
}

// Round 6
// 4069.572 us; speedup vs baseline: 1.4562x; 1.0340x over previous
//
#include <hip/hip_runtime.h>

// ---- problem constants -----------------------------------------------------
#define BTOT   4096      // batch
#define TWARM  64        // warm timesteps
#define FIN    64        // input features
#define UDIM   256       // hidden units
#define ZDIM   1024      // 4*U gate pre-activations
#define KDIM   320       // FIN + UDIM
#define OSTEPS 24
#define OCOLS  65        // dense out dim (F+1)
#define BR     16        // batch rows per block -> 256 blocks, 1 per CU
#define NB     (BTOT / BR)
#define ASTR   344       // LDS A row stride in bf16 (320 + 24 pad)
#define NTHR   1024      // 16 waves
#define DLDS   (5 * 8 * 1024)   // dense weights staged in LDS (80 KB)
// R6: W register-stationary, PINNED via empty inline-asm redefinition so LLVM
// cannot rematerialize the global loads back into the step loop (R5 failure:
// VGPR_Count=64, W re-streamed from HBM every step at 2.8 TB/s).
// Wp layout: ((wv*4+g)*10+kt)*1024 + lcol*64 + lrow*16 + hl*8 + j
// Dp layout: ((ct*8+kt)*1024)      + lcol*64 + lrow*16 + hl*8 + j  (ct 0..4)

typedef short bf16x8 __attribute__((ext_vector_type(8)));
typedef short s16x4  __attribute__((ext_vector_type(4)));
typedef float f32x4  __attribute__((ext_vector_type(4)));

static __device__ __forceinline__ short f2bf(float x) {  // RNE f32 -> bf16 bits
  unsigned u = __float_as_uint(x);
  return (short)((u + 0x7fffu + ((u >> 16) & 1u)) >> 16);
}
static __device__ __forceinline__ float bf2f(short h) {
  return __uint_as_float(((unsigned)(unsigned short)h) << 16);
}
static __device__ __forceinline__ float sigm(float x) {
  return 1.0f / (1.0f + __expf(-x));
}
static __device__ __forceinline__ float tanh_(float x) {
  return 2.0f / (1.0f + __expf(-2.0f * x)) - 1.0f;
}
// Opaque redefinition: value becomes an asm result -> not rematerializable.
static __device__ __forceinline__ void pin(bf16x8& v) {
  asm volatile("" : "+v"(v));
}

// ---- weight repack into per-wave register-fragment order --------------------
__global__ void pack_w_kernel(const float* __restrict__ kern,
                              const float* __restrict__ rec,
                              short* __restrict__ Wp) {
  const int col = blockIdx.x;   // 0..1023 (zcol)
  const int k   = threadIdx.x;  // 0..319
  const float w = (k < FIN) ? kern[k * ZDIM + col] : rec[(k - FIN) * ZDIM + col];
  const short hi = f2bf(w);
  const int g    = col >> 8;
  const int wvp  = (col >> 4) & 15;
  const int lc   = col & 15;
  const int kt   = k >> 5;
  const int lr   = (k >> 3) & 3;
  const int j    = k & 7;
  const int base = ((wvp * 4 + g) * 10 + kt) * 1024 + lc * 64 + lr * 16 + j;
  Wp[base]     = hi;
  Wp[base + 8] = f2bf(w - bf2f(hi));
}

__global__ void pack_dw_kernel(const float* __restrict__ dw,
                               short* __restrict__ Dp) {
  const int col = blockIdx.x;   // 0..79 (>=65 zero-padded)
  const int k   = threadIdx.x;  // 0..255
  const float w = (col < OCOLS) ? dw[k * OCOLS + col] : 0.0f;
  const short hi = f2bf(w);
  const int ct = col >> 4;
  const int lc = col & 15;
  const int kt = k >> 5;
  const int lr = (k >> 3) & 3;
  const int j  = k & 7;
  const int base = (ct * 8 + kt) * 1024 + lc * 64 + lr * 16 + j;
  Dp[base]     = hi;
  Dp[base + 8] = f2bf(w - bf2f(hi));
}

// ---- persistent LSTM + AR kernel: W pinned in registers ---------------------
__global__ __launch_bounds__(NTHR, 4) void lstm_ar_kernel(
    const float* __restrict__ inputs, const float* __restrict__ bias,
    const float* __restrict__ dense_b, const short* __restrict__ Wp,
    const short* __restrict__ Dp, float* __restrict__ out) {
  __shared__ short Ah[BR * ASTR];   // A = [x(0:64) | h(64:320)] bf16 hi
  __shared__ short Al[BR * ASTR];   // bf16 lo residual
  __shared__ short Dlds[DLDS];      // dense W hi|lo, 80 KB

  const int tid  = (int)threadIdx.x;
  const int wv   = tid >> 6;        // wave 0..15
  const int lane = tid & 63;
  const int lrow = lane >> 4;       // k-group 0..3
  const int lcol = lane & 15;
  const int b0   = (int)blockIdx.x * BR;
  const int laneoff = lcol * 64 + lrow * 16;

  // ---- load stationary W: 80 x bf16x8 = 320 VGPRs, once, reused 88 steps ----
  bf16x8 wh[4][10], wl[4][10];
#pragma unroll
  for (int g = 0; g < 4; ++g)
#pragma unroll
    for (int kt = 0; kt < 10; ++kt) {
      const short* p = Wp + ((wv * 4 + g) * 10 + kt) * 1024 + laneoff;
      wh[g][kt] = *reinterpret_cast<const bf16x8*>(p);
      wl[g][kt] = *reinterpret_cast<const bf16x8*>(p + 8);
      pin(wh[g][kt]);               // forbid remat: keep resident all 88 steps
      pin(wl[g][kt]);
    }

  // dense W -> LDS (5120 x 16B, 5 per thread); frees 64 VGPRs vs reg-resident
  for (int i = tid; i < DLDS / 8; i += NTHR)
    reinterpret_cast<bf16x8*>(Dlds)[i] = reinterpret_cast<const bf16x8*>(Dp)[i];

  float dbz = 0.0f;
  if (wv < 5) {
    const int col = wv * 16 + lcol;
    dbz = (col < OCOLS) ? dense_b[col] : 0.0f;
  }
  float bz[4];
#pragma unroll
  for (int g = 0; g < 4; ++g)
    bz[g] = bias[g * UDIM + wv * 16 + lcol];

  // cell state, C/D layout: row = lrow*4+q, u = wv*16+lcol
  f32x4 cst; cst[0] = 0.f; cst[1] = 0.f; cst[2] = 0.f; cst[3] = 0.f;

  // stage x_t: 16 rows x 16 float4 = 256 loads (threads 0..255)
  auto stage_x = [&](int t) {
    if (tid < 256) {
      const int r  = tid >> 4;
      const int c4 = (tid & 15) << 2;
      const float4 v = *reinterpret_cast<const float4*>(
          inputs + (size_t)(b0 + r) * (TWARM * FIN) + (size_t)t * FIN + c4);
      s16x4 hi, lo;
      hi[0] = f2bf(v.x); lo[0] = f2bf(v.x - bf2f(hi[0]));
      hi[1] = f2bf(v.y); lo[1] = f2bf(v.y - bf2f(hi[1]));
      hi[2] = f2bf(v.z); lo[2] = f2bf(v.z - bf2f(hi[2]));
      hi[3] = f2bf(v.w); lo[3] = f2bf(v.w - bf2f(hi[3]));
      *reinterpret_cast<s16x4*>(&Ah[r * ASTR + c4]) = hi;
      *reinterpret_cast<s16x4*>(&Al[r * ASTR + c4]) = lo;
    }
  };

  // one LSTM step: zero global loads. 20 ds_read_b128 + 120 MFMA per wave.
  auto lstm_step = [&]() {
    f32x4 acc[4];
#pragma unroll
    for (int g = 0; g < 4; ++g) {
      acc[g][0] = bz[g]; acc[g][1] = bz[g]; acc[g][2] = bz[g]; acc[g][3] = bz[g];
    }
#pragma unroll
    for (int kt = 0; kt < 10; ++kt) {
      const int aoff = lcol * ASTR + kt * 32 + lrow * 8;
      const bf16x8 ah = *reinterpret_cast<const bf16x8*>(&Ah[aoff]);
      const bf16x8 al = *reinterpret_cast<const bf16x8*>(&Al[aoff]);
#pragma unroll
      for (int g = 0; g < 4; ++g) {
        acc[g] = __builtin_amdgcn_mfma_f32_16x16x32_bf16(ah, wh[g][kt], acc[g], 0, 0, 0);
        acc[g] = __builtin_amdgcn_mfma_f32_16x16x32_bf16(al, wh[g][kt], acc[g], 0, 0, 0);
        acc[g] = __builtin_amdgcn_mfma_f32_16x16x32_bf16(ah, wl[g][kt], acc[g], 0, 0, 0);
      }
    }
    __syncthreads();  // all waves done reading A before h is overwritten
#pragma unroll
    for (int q = 0; q < 4; ++q) {
      const float iv = sigm(acc[0][q]);
      const float fv = sigm(acc[1][q]);
      const float gv = tanh_(acc[2][q]);
      const float ov = sigm(acc[3][q]);
      const float c  = fv * cst[q] + iv * gv;
      cst[q] = c;
      const float h  = ov * tanh_(c);
      const int row  = lrow * 4 + q;
      const int u    = wv * 16 + lcol;
      const short hi = f2bf(h);
      Ah[row * ASTR + FIN + u] = hi;
      Al[row * ASTR + FIN + u] = f2bf(h - bf2f(hi));
    }
  };

  // init: zero A (h0 = 0), stage x_0
  for (int i = tid; i < BR * ASTR; i += NTHR) { Ah[i] = 0; Al[i] = 0; }
  __syncthreads();
  stage_x(0);
  __syncthreads();

  // ---- warm phase ----
#pragma unroll 1
  for (int t = 0; t < TWARM; ++t) {
    lstm_step();
    if (t + 1 < TWARM) stage_x(t + 1);   // x region disjoint from h region
    __syncthreads();
  }

  // ---- autoregressive phase ----
#pragma unroll 1
  for (int s = 0; s < OSTEPS; ++s) {
    // dense on waves 0..4 (ct = wv): reads A h-region + Dlds, writes x / out
    if (wv < 5) {
      f32x4 p; p[0] = dbz; p[1] = dbz; p[2] = dbz; p[3] = dbz;
#pragma unroll
      for (int kt = 0; kt < 8; ++kt) {
        const int aoff = lcol * ASTR + FIN + kt * 32 + lrow * 8;
        const bf16x8 ah = *reinterpret_cast<const bf16x8*>(&Ah[aoff]);
        const bf16x8 al = *reinterpret_cast<const bf16x8*>(&Al[aoff]);
        const int doff = (wv * 8 + kt) * 1024 + laneoff;
        const bf16x8 dh = *reinterpret_cast<const bf16x8*>(&Dlds[doff]);
        const bf16x8 dl = *reinterpret_cast<const bf16x8*>(&Dlds[doff + 8]);
        p = __builtin_amdgcn_mfma_f32_16x16x32_bf16(ah, dh, p, 0, 0, 0);
        p = __builtin_amdgcn_mfma_f32_16x16x32_bf16(al, dh, p, 0, 0, 0);
        p = __builtin_amdgcn_mfma_f32_16x16x32_bf16(ah, dl, p, 0, 0, 0);
      }
      if (wv < 4) {       // x_next = pred[:, 0:64]
#pragma unroll
        for (int q = 0; q < 4; ++q) {
          const float v  = p[q];
          const int row  = lrow * 4 + q;
          const int col  = wv * 16 + lcol;
          const short hi = f2bf(v);
          Ah[row * ASTR + col] = hi;
          Al[row * ASTR + col] = f2bf(v - bf2f(hi));
        }
      } else if (lcol == 0) {  // col 64 = the output column
#pragma unroll
        for (int q = 0; q < 4; ++q)
          out[(size_t)(b0 + lrow * 4 + q) * OSTEPS + s] = p[q];
      }
    }
    __syncthreads();
    if (s + 1 < OSTEPS) {
      lstm_step();
      __syncthreads();
    }
  }
}

// ---- launch ---------------------------------------------------------------
extern "C" void kernel_launch(void* const* d_in, const int* in_sizes, int n_in,
                              void* d_out, int out_size, void* d_ws, size_t ws_size,
                              hipStream_t stream) {
  (void)in_sizes; (void)n_in; (void)out_size; (void)ws_size;
  const float* inputs = (const float*)d_in[0];
  const float* kern   = (const float*)d_in[1];
  const float* rec    = (const float*)d_in[2];
  const float* bias   = (const float*)d_in[3];
  const float* dw     = (const float*)d_in[4];
  const float* db     = (const float*)d_in[5];
  float* out = (float*)d_out;

  short* Wp = (short*)d_ws;              // 16*4*10*1024 shorts = 1.31 MB
  short* Dp = Wp + 16 * 4 * 10 * 1024;   // 5*8*1024 shorts    = 82 KB

  hipLaunchKernelGGL(pack_w_kernel,  dim3(ZDIM), dim3(KDIM), 0, stream, kern, rec, Wp);
  hipLaunchKernelGGL(pack_dw_kernel, dim3(80),   dim3(UDIM), 0, stream, dw, Dp);
  hipLaunchKernelGGL(lstm_ar_kernel, dim3(NB), dim3(NTHR), 0, stream,
                     inputs, bias, db, Wp, Dp, out);
}

// Round 7
// 2638.081 us; speedup vs baseline: 2.2464x; 1.5426x over previous
//
#include <hip/hip_runtime.h>

// ---- problem constants -----------------------------------------------------
#define BTOT   4096      // batch
#define TWARM  64        // warm timesteps
#define FIN    64        // input features
#define UDIM   256       // hidden units
#define ZDIM   1024      // 4*U gate pre-activations
#define KDIM   320       // FIN + UDIM
#define OSTEPS 24
#define OCOLS  65        // dense out dim (F+1)
#define BR     16        // batch rows per block -> 256 blocks, 1 per CU
#define NB     (BTOT / BR)
#define ASTR   344       // LDS A row stride in bf16 (320 + 24 pad)
#define NTHR   1024      // 16 waves
#define RING   3         // per-wave LDS ring slots (frag = 2 KB)
#define NFRAG  40        // 10 kt x 4 gates; frag f: kt=f>>2, gate=f&3
// R7: RF is 512 KB/CU (m69) -> W can NEVER be register-stationary. Stream W
// from L2 through per-wave private LDS rings via global_load_lds (no VGPR
// round-trip, no barriers in the K-loop, counted vmcnt for 2-deep pipeline).
// Wp layout: frag-linear. frag = (kt*4+g)*16 + wv owns 1024 shorts:
//   [0,512)  = hi bf16x8 per lane (lane = lrow*16+lcol, 8 shorts each)
//   [512,1024) = lo residual, same order.
// Dp layout (dense): (ct*8+kt)*1024 + lcol*64 + lrow*16 + hl*8 + j (ct 0..4)

typedef short bf16x8 __attribute__((ext_vector_type(8)));
typedef short s16x4  __attribute__((ext_vector_type(4)));
typedef float f32x4  __attribute__((ext_vector_type(4)));

static __device__ __forceinline__ short f2bf(float x) {  // RNE f32 -> bf16 bits
  unsigned u = __float_as_uint(x);
  return (short)((u + 0x7fffu + ((u >> 16) & 1u)) >> 16);
}
static __device__ __forceinline__ float bf2f(short h) {
  return __uint_as_float(((unsigned)(unsigned short)h) << 16);
}
static __device__ __forceinline__ float sigm(float x) {
  return 1.0f / (1.0f + __expf(-x));
}
static __device__ __forceinline__ float tanh_(float x) {
  return 2.0f / (1.0f + __expf(-2.0f * x)) - 1.0f;
}
// async global->LDS, 16B per lane; lds dest is wave-uniform base + lane*16
static __device__ __forceinline__ void gload_lds16(const short* g, short* l) {
  __builtin_amdgcn_global_load_lds(
      (const __attribute__((address_space(1))) void*)g,
      (__attribute__((address_space(3))) void*)l, 16, 0, 0);
}

// ---- weight repack into frag-linear DMA order -------------------------------
__global__ void pack_w_kernel(const float* __restrict__ kern,
                              const float* __restrict__ rec,
                              short* __restrict__ Wp) {
  const int col = blockIdx.x;   // 0..1023 (zcol)
  const int k   = threadIdx.x;  // 0..319
  const float w = (k < FIN) ? kern[k * ZDIM + col] : rec[(k - FIN) * ZDIM + col];
  const short hi = f2bf(w);
  const int g  = col >> 8;
  const int u  = col & 255;
  const int wv = u >> 4;
  const int lc = u & 15;
  const int kt = k >> 5;
  const int lr = (k >> 3) & 3;
  const int j  = k & 7;
  const int base = ((kt * 4 + g) * 16 + wv) * 1024 + (lr * 16 + lc) * 8 + j;
  Wp[base]       = hi;
  Wp[base + 512] = f2bf(w - bf2f(hi));
}

__global__ void pack_dw_kernel(const float* __restrict__ dw,
                               short* __restrict__ Dp) {
  const int col = blockIdx.x;   // 0..79 (>=65 zero-padded)
  const int k   = threadIdx.x;  // 0..255
  const float w = (col < OCOLS) ? dw[k * OCOLS + col] : 0.0f;
  const short hi = f2bf(w);
  const int ct = col >> 4;
  const int lc = col & 15;
  const int kt = k >> 5;
  const int lr = (k >> 3) & 3;
  const int j  = k & 7;
  const int base = (ct * 8 + kt) * 1024 + lc * 64 + lr * 16 + j;
  Dp[base]     = hi;
  Dp[base + 8] = f2bf(w - bf2f(hi));
}

// ---- persistent LSTM + AR kernel: W streamed L2->LDS, wave-private rings ----
__global__ __launch_bounds__(NTHR, 4) void lstm_ar_kernel(
    const float* __restrict__ inputs, const float* __restrict__ bias,
    const float* __restrict__ dense_b, const short* __restrict__ Wp,
    const short* __restrict__ Dp, float* __restrict__ out) {
  __shared__ short Ah[BR * ASTR];          // A = [x(0:64)|h(64:320)] bf16 hi
  __shared__ short Al[BR * ASTR];          // bf16 lo residual
  __shared__ short Wring[16 * RING * 1024]; // per-wave 3-slot DMA ring (96 KB)

  const int tid  = (int)threadIdx.x;
  const int wv   = tid >> 6;        // wave 0..15; owns u in [wv*16, wv*16+16)
  const int lane = tid & 63;
  const int lrow = lane >> 4;       // k-group 0..3
  const int lcol = lane & 15;
  const int b0   = (int)blockIdx.x * BR;

  float bz[4];
#pragma unroll
  for (int g = 0; g < 4; ++g)
    bz[g] = bias[g * UDIM + wv * 16 + lcol];
  float dbz = 0.0f;
  if (wv < 5) {
    const int col = wv * 16 + lcol;
    dbz = (col < OCOLS) ? dense_b[col] : 0.0f;
  }

  // cell state, C/D layout: row = lrow*4+q, u = wv*16+lcol
  f32x4 cst; cst[0] = 0.f; cst[1] = 0.f; cst[2] = 0.f; cst[3] = 0.f;

  // issue one 2 KB frag (hi 1 KB + lo 1 KB) into this wave's ring slot
  auto issue_frag = [&](int f, int slot) {
    const short* gs = Wp + (f * 16 + wv) * 1024 + lane * 8;  // per-lane 16 B
    short* ls = &Wring[(wv * RING + slot) * 1024];           // wave-uniform
    gload_lds16(gs, ls);
    gload_lds16(gs + 512, ls + 512);
  };

  // stage x_t: 16 rows x 16 float4 = 256 loads (threads 0..255)
  auto stage_x = [&](int t) {
    if (tid < 256) {
      const int r  = tid >> 4;
      const int c4 = (tid & 15) << 2;
      const float4 v = *reinterpret_cast<const float4*>(
          inputs + (size_t)(b0 + r) * (TWARM * FIN) + (size_t)t * FIN + c4);
      s16x4 hi, lo;
      hi[0] = f2bf(v.x); lo[0] = f2bf(v.x - bf2f(hi[0]));
      hi[1] = f2bf(v.y); lo[1] = f2bf(v.y - bf2f(hi[1]));
      hi[2] = f2bf(v.z); lo[2] = f2bf(v.z - bf2f(hi[2]));
      hi[3] = f2bf(v.w); lo[3] = f2bf(v.w - bf2f(hi[3]));
      *reinterpret_cast<s16x4*>(&Ah[r * ASTR + c4]) = hi;
      *reinterpret_cast<s16x4*>(&Al[r * ASTR + c4]) = lo;
    }
  };

  // one LSTM step. Per wave: 40 frags, each {vmcnt-wait, 2 ds_read_b128,
  // lgkm(0), reissue slot, 3 MFMA}. No barriers inside the frag loop.
  auto lstm_step = [&]() {
    f32x4 acc[4];
#pragma unroll
    for (int g = 0; g < 4; ++g) {
      acc[g][0] = bz[g]; acc[g][1] = bz[g]; acc[g][2] = bz[g]; acc[g][3] = bz[g];
    }
    issue_frag(0, 0); issue_frag(1, 1); issue_frag(2, 2);
    bf16x8 ah{}, al{};
#pragma unroll
    for (int f = 0; f < NFRAG; ++f) {
      const int kt = f >> 2, g = f & 3, slot = f % RING;
      if (g == 0) {
        const int aoff = lcol * ASTR + kt * 32 + lrow * 8;
        ah = *reinterpret_cast<const bf16x8*>(&Ah[aoff]);
        al = *reinterpret_cast<const bf16x8*>(&Al[aoff]);
      }
      // frag f resident when <= (pairs beyond f) outstanding
      if (f <= 37)      asm volatile("s_waitcnt vmcnt(4)" ::: "memory");
      else if (f == 38) asm volatile("s_waitcnt vmcnt(2)" ::: "memory");
      else              asm volatile("s_waitcnt vmcnt(0)" ::: "memory");
      const short* wb = &Wring[(wv * RING + slot) * 1024 + lane * 8];
      const bf16x8 wh = *reinterpret_cast<const bf16x8*>(wb);
      const bf16x8 wl = *reinterpret_cast<const bf16x8*>(wb + 512);
      // ds_reads complete before this slot's DMA reissue (ring reuse safety)
      asm volatile("s_waitcnt lgkmcnt(0)" ::: "memory");
      if (f + RING < NFRAG) issue_frag(f + RING, slot);
      acc[g] = __builtin_amdgcn_mfma_f32_16x16x32_bf16(ah, wh, acc[g], 0, 0, 0);
      acc[g] = __builtin_amdgcn_mfma_f32_16x16x32_bf16(al, wh, acc[g], 0, 0, 0);
      acc[g] = __builtin_amdgcn_mfma_f32_16x16x32_bf16(ah, wl, acc[g], 0, 0, 0);
    }
    __syncthreads();  // all waves done reading A before h is overwritten
#pragma unroll
    for (int q = 0; q < 4; ++q) {
      const float iv = sigm(acc[0][q]);
      const float fv = sigm(acc[1][q]);
      const float gv = tanh_(acc[2][q]);
      const float ov = sigm(acc[3][q]);
      const float c  = fv * cst[q] + iv * gv;
      cst[q] = c;
      const float h  = ov * tanh_(c);
      const int row  = lrow * 4 + q;
      const int u    = wv * 16 + lcol;
      const short hi = f2bf(h);
      Ah[row * ASTR + FIN + u] = hi;
      Al[row * ASTR + FIN + u] = f2bf(h - bf2f(hi));
    }
  };

  // init: zero A (h0 = 0), stage x_0
  for (int i = tid; i < BR * ASTR; i += NTHR) { Ah[i] = 0; Al[i] = 0; }
  __syncthreads();
  stage_x(0);
  __syncthreads();

  // ---- warm phase ----
#pragma unroll 1
  for (int t = 0; t < TWARM; ++t) {
    lstm_step();
    if (t + 1 < TWARM) stage_x(t + 1);   // x region disjoint from h region
    __syncthreads();
  }

  // ---- autoregressive phase ----
#pragma unroll 1
  for (int s = 0; s < OSTEPS; ++s) {
    // dense on waves 0..4 (ct = wv): reads A h-region + Dp, writes x / out
    if (wv < 5) {
      f32x4 p; p[0] = dbz; p[1] = dbz; p[2] = dbz; p[3] = dbz;
      const int laneoff = lcol * 64 + lrow * 16;
#pragma unroll
      for (int kt = 0; kt < 8; ++kt) {
        const int aoff = lcol * ASTR + FIN + kt * 32 + lrow * 8;
        const bf16x8 ah = *reinterpret_cast<const bf16x8*>(&Ah[aoff]);
        const bf16x8 al = *reinterpret_cast<const bf16x8*>(&Al[aoff]);
        const int doff = (wv * 8 + kt) * 1024 + laneoff;
        const bf16x8 dh = *reinterpret_cast<const bf16x8*>(Dp + doff);
        const bf16x8 dl = *reinterpret_cast<const bf16x8*>(Dp + doff + 8);
        p = __builtin_amdgcn_mfma_f32_16x16x32_bf16(ah, dh, p, 0, 0, 0);
        p = __builtin_amdgcn_mfma_f32_16x16x32_bf16(al, dh, p, 0, 0, 0);
        p = __builtin_amdgcn_mfma_f32_16x16x32_bf16(ah, dl, p, 0, 0, 0);
      }
      if (wv < 4) {       // x_next = pred[:, 0:64]
#pragma unroll
        for (int q = 0; q < 4; ++q) {
          const float v  = p[q];
          const int row  = lrow * 4 + q;
          const int col  = wv * 16 + lcol;
          const short hi = f2bf(v);
          Ah[row * ASTR + col] = hi;
          Al[row * ASTR + col] = f2bf(v - bf2f(hi));
        }
      } else if (lcol == 0) {  // col 64 = the output column
#pragma unroll
        for (int q = 0; q < 4; ++q)
          out[(size_t)(b0 + lrow * 4 + q) * OSTEPS + s] = p[q];
      }
    }
    __syncthreads();
    if (s + 1 < OSTEPS) {
      lstm_step();
      __syncthreads();
    }
  }
}

// ---- launch ---------------------------------------------------------------
extern "C" void kernel_launch(void* const* d_in, const int* in_sizes, int n_in,
                              void* d_out, int out_size, void* d_ws, size_t ws_size,
                              hipStream_t stream) {
  (void)in_sizes; (void)n_in; (void)out_size; (void)ws_size;
  const float* inputs = (const float*)d_in[0];
  const float* kern   = (const float*)d_in[1];
  const float* rec    = (const float*)d_in[2];
  const float* bias   = (const float*)d_in[3];
  const float* dw     = (const float*)d_in[4];
  const float* db     = (const float*)d_in[5];
  float* out = (float*)d_out;

  short* Wp = (short*)d_ws;              // 640 frags * 1024 shorts = 1.31 MB
  short* Dp = Wp + NFRAG * 16 * 1024;    // 5*8*1024 shorts = 82 KB

  hipLaunchKernelGGL(pack_w_kernel,  dim3(ZDIM), dim3(KDIM), 0, stream, kern, rec, Wp);
  hipLaunchKernelGGL(pack_dw_kernel, dim3(80),   dim3(UDIM), 0, stream, dw, Dp);
  hipLaunchKernelGGL(lstm_ar_kernel, dim3(NB), dim3(NTHR), 0, stream,
                     inputs, bias, db, Wp, Dp, out);
}